// Round 9
// baseline (526.663 us; speedup 1.0000x reference)
//
#include <hip/hip_runtime.h>
#include <hip/hip_bf16.h>
#include <hip/hip_cooperative_groups.h>

namespace cg = cooperative_groups;

#define NN 65536
#define DD 512
#define HH 512
#define NSTEP 4
#define NEG_INFF -100000000.0f

#define RPW 16                 // rows per wave in attention phases
#define NWAVE 4096             // 4096 waves x 16 rows = 65536
#define ABLOCKS 1024           // fallback attn grid (256-thread blocks)
#define MEGA_BLOCKS 512        // cooperative grid (512-thread blocks)

typedef unsigned short ushort_t;
typedef __attribute__((ext_vector_type(8))) short bf16x8;
typedef __attribute__((ext_vector_type(4))) float f32x4;

// ---------- helpers ----------
__device__ __forceinline__ float bflo(unsigned u) {
    union { unsigned i; float f; } v; v.i = u << 16; return v.f;
}
__device__ __forceinline__ float bfhi(unsigned u) {
    union { unsigned i; float f; } v; v.i = u & 0xffff0000u; return v.f;
}
__device__ __forceinline__ float fast_tanh(float x) {
    float e = __expf(2.0f * x);
    return 1.0f - 2.0f * __builtin_amdgcn_rcpf(e + 1.0f);
}

#define GL2LDS(g, l) __builtin_amdgcn_global_load_lds( \
    (const __attribute__((address_space(1))) unsigned int*)(g), \
    (__attribute__((address_space(3))) unsigned int*)(l), 16, 0, 0)

// ---------- f32 -> bf16 convert (attn_mem) ----------
__global__ __launch_bounds__(256)
void conv_bf16(const float* __restrict__ in, ushort_t* __restrict__ out) {
    const int i = blockIdx.x * 256 + threadIdx.x;
    const size_t base = (size_t)i * 8;
    float4 a = *(const float4*)&in[base];
    float4 b = *(const float4*)&in[base + 4];
    union { __hip_bfloat16 h[8]; uint4 u; } t;
    t.h[0] = __float2bfloat16(a.x); t.h[1] = __float2bfloat16(a.y);
    t.h[2] = __float2bfloat16(a.z); t.h[3] = __float2bfloat16(a.w);
    t.h[4] = __float2bfloat16(b.x); t.h[5] = __float2bfloat16(b.y);
    t.h[6] = __float2bfloat16(b.z); t.h[7] = __float2bfloat16(b.w);
    *(uint4*)&out[base] = t.u;
}

// ---------- weight transpose + convert: WT[n][k] = bf16(W[k][n]) ----------
__global__ __launch_bounds__(256)
void conv_wt(const float* __restrict__ W0, const float* __restrict__ W1,
             ushort_t* __restrict__ T0, ushort_t* __restrict__ T1) {
    const float* W = blockIdx.y ? W1 : W0;
    ushort_t* T = blockIdx.y ? T1 : T0;
    const int n = blockIdx.x * 4 + (threadIdx.x >> 6);
    const int k0 = (threadIdx.x & 63) * 8;
    union { __hip_bfloat16 h[8]; uint4 u; } t;
#pragma unroll
    for (int i = 0; i < 8; ++i)
        t.h[i] = __float2bfloat16(W[(size_t)(k0 + i) * HH + n]);
    *(uint4*)&T[(size_t)n * DD + k0] = t.u;
}

// ---------- MFMA GEMM: XCD-locality grid + 2-phase LDS double-buffer ----------
#define TM 128
#define TK 32
#define NT (DD / TK)   // 16 K-steps
__global__ __launch_bounds__(256)
void gemm_mfma(const ushort_t* __restrict__ A,
               const ushort_t* __restrict__ WT0, const ushort_t* __restrict__ WT1,
               __hip_bfloat16* __restrict__ C0, __hip_bfloat16* __restrict__ C1) {
    __shared__ ushort_t As[2][TM * TK];
    __shared__ ushort_t Bs[2][TM * TK];
    const int L = blockIdx.x;
    const int xcd = L & 7;
    const int slot = L >> 3;
    const int mt = xcd * 64 + (slot >> 3);
    const int my = slot & 7;
    const ushort_t* WT = (my < 4) ? WT0 : WT1;
    __hip_bfloat16* Cp = (my < 4) ? C0 : C1;
    const int bn = (my & 3) * TM;
    const int bm = mt * TM;
    const int tid = threadIdx.x;
    const int lane = tid & 63;
    const int wid = tid >> 6;
    const int wr = (wid >> 1) * 64;
    const int wc = (wid & 1) * 64;
    const int l15 = lane & 15;
    const int srow = lane >> 2;
    const int ske = (((lane & 3) ^ ((lane >> 3) & 3)) * 8);
    const int koff = (((lane >> 4) ^ ((l15 >> 1) & 3)) << 3);

    const ushort_t* Abase = A + (size_t)bm * DD;
    const ushort_t* Bbase = WT + (size_t)bn * DD;

    auto stage = [&](int b, int k0) {
#pragma unroll
        for (int u = 0; u < 2; ++u) {
            const int g = u * 4 + wid;
            const int row = g * 16 + srow;
            GL2LDS(Abase + (size_t)row * DD + k0 + ske, &As[b][g * 512]);
            GL2LDS(Bbase + (size_t)row * DD + k0 + ske, &Bs[b][g * 512]);
        }
    };

    const f32x4 zero = {0.f, 0.f, 0.f, 0.f};
    f32x4 acc[4][4];
#pragma unroll
    for (int m = 0; m < 4; ++m)
#pragma unroll
        for (int n = 0; n < 4; ++n) acc[m][n] = zero;

    stage(0, 0);
    stage(1, TK);
    __builtin_amdgcn_sched_barrier(0);

    for (int t = 0; t < NT; ++t) {
        const int cur = t & 1;
        if (t + 1 < NT) asm volatile("s_waitcnt vmcnt(4)" ::: "memory");
        else            asm volatile("s_waitcnt vmcnt(0)" ::: "memory");
        __builtin_amdgcn_sched_barrier(0);
        __builtin_amdgcn_s_barrier();
        __builtin_amdgcn_sched_barrier(0);

        bf16x8 af[4], bfr[4];
#pragma unroll
        for (int m = 0; m < 4; ++m)
            af[m] = *(const bf16x8*)(&As[cur][(wr + m * 16 + l15) * TK + koff]);
#pragma unroll
        for (int n = 0; n < 4; ++n)
            bfr[n] = *(const bf16x8*)(&Bs[cur][(wc + n * 16 + l15) * TK + koff]);
#pragma unroll
        for (int m = 0; m < 4; ++m)
#pragma unroll
            for (int n = 0; n < 4; ++n)
                acc[m][n] = __builtin_amdgcn_mfma_f32_16x16x32_bf16(af[m], bfr[n], acc[m][n], 0, 0, 0);

        asm volatile("s_waitcnt lgkmcnt(0)" ::: "memory");
        __builtin_amdgcn_sched_barrier(0);
        __builtin_amdgcn_s_barrier();
        __builtin_amdgcn_sched_barrier(0);
        if (t + 2 < NT) stage(cur, (t + 2) * TK);
        __builtin_amdgcn_sched_barrier(0);
    }

    const int r0 = (lane >> 4) * 4;
#pragma unroll
    for (int m = 0; m < 4; ++m) {
#pragma unroll
        for (int n = 0; n < 4; ++n) {
            const f32x4 vv = acc[m][n];
            const size_t cb = (size_t)(bm + wr + m * 16 + r0) * HH + bn + wc + n * 16 + l15;
#pragma unroll
            for (int r = 0; r < 4; ++r)
                Cp[cb + (size_t)r * HH] = __float2bfloat16(vv[r]);
        }
    }
}

// ---------- attention core: 4-deep prefetch ring, returns acc[8], lsum ----------
template<bool HOP>
__device__ __forceinline__
void attn_core(const ushort_t* __restrict__ feat, const ushort_t* __restrict__ mem,
               const float* __restrict__ qw, const float* __restrict__ v,
               const int* __restrict__ mask, int wave, int lane,
               float acc[8], float& lsum) {
    float qv[8], vv[8];
    {
        float4 q0 = *(const float4*)&qw[lane * 8];
        float4 q1 = *(const float4*)&qw[lane * 8 + 4];
        qv[0] = q0.x; qv[1] = q0.y; qv[2] = q0.z; qv[3] = q0.w;
        qv[4] = q1.x; qv[5] = q1.y; qv[6] = q1.z; qv[7] = q1.w;
        float4 v0 = *(const float4*)&v[lane * 8];
        float4 v1 = *(const float4*)&v[lane * 8 + 4];
        vv[0] = v0.x; vv[1] = v0.y; vv[2] = v0.z; vv[3] = v0.w;
        vv[4] = v1.x; vv[5] = v1.y; vv[6] = v1.z; vv[7] = v1.w;
    }
    float C = 0.f;
#pragma unroll
    for (int j = 0; j < 8; ++j) C += fabsf(vv[j]);
#pragma unroll
    for (int o = 32; o; o >>= 1) C += __shfl_xor(C, o, 64);

    lsum = 0.f;
#pragma unroll
    for (int j = 0; j < 8; ++j) acc[j] = 0.f;
    const int row0 = wave * RPW;

    uint4 fb[4], mb[4];
#pragma unroll
    for (int r = 0; r < 4; ++r) {
        fb[r] = *(const uint4*)(feat + (size_t)(row0 + r) * HH + lane * 8);
        if (!HOP) mb[r] = *(const uint4*)(mem + (size_t)(row0 + r) * DD + lane * 8);
    }
#pragma unroll
    for (int r = 0; r < RPW; ++r) {
        const uint4 fc = fb[r & 3];
        uint4 mc;
        if (!HOP) mc = mb[r & 3];
        if (r + 4 < RPW) {
            fb[r & 3] = *(const uint4*)(feat + (size_t)(row0 + r + 4) * HH + lane * 8);
            if (!HOP) mb[r & 3] = *(const uint4*)(mem + (size_t)(row0 + r + 4) * DD + lane * 8);
        }
        float f[8];
        f[0] = bflo(fc.x); f[1] = bfhi(fc.x); f[2] = bflo(fc.y); f[3] = bfhi(fc.y);
        f[4] = bflo(fc.z); f[5] = bfhi(fc.z); f[6] = bflo(fc.w); f[7] = bfhi(fc.w);
        float mv[8];
        if (!HOP) {
            mv[0] = bflo(mc.x); mv[1] = bfhi(mc.x); mv[2] = bflo(mc.y); mv[3] = bfhi(mc.y);
            mv[4] = bflo(mc.z); mv[5] = bfhi(mc.z); mv[6] = bflo(mc.w); mv[7] = bfhi(mc.w);
        } else {
#pragma unroll
            for (int j = 0; j < 8; ++j) mv[j] = f[j];
        }
        float d = 0.f;
#pragma unroll
        for (int j = 0; j < 8; ++j) d += fast_tanh(f[j] + qv[j]) * vv[j];
#pragma unroll
        for (int o = 32; o; o >>= 1) d += __shfl_xor(d, o, 64);
        const float sc = d - C + (mask[row0 + r] ? 0.f : NEG_INFF);
        const float p = __expf(sc);
        lsum += p;
#pragma unroll
        for (int j = 0; j < 8; ++j) acc[j] += p * mv[j];
    }
}

// ---------- combine body (fallback path) ----------
__device__ __forceinline__
void combine_body(const float* __restrict__ pl, const float* __restrict__ pacc,
                  float* __restrict__ out, float* __restrict__ sh,
                  int c0, int tid, int nthr) {
    const int lane = tid & 63, wv = tid >> 6;
    const int nw = nthr >> 6;
    float lg = 0.f;
    for (int b = tid; b < NWAVE; b += nthr) lg += pl[b];
#pragma unroll
    for (int o = 32; o; o >>= 1) lg += __shfl_xor(lg, o, 64);
    if (lane == 0) sh[wv] = lg;
    __syncthreads();
    float lt = 0.f;
    for (int r = 0; r < nw; ++r) lt += sh[r];
    const float inv = 1.0f / lt;
    __syncthreads();
    float a[8];
#pragma unroll
    for (int j = 0; j < 8; ++j) a[j] = 0.f;
    for (int b = tid; b < NWAVE; b += nthr) {
        float4 p0 = *(const float4*)&pacc[(size_t)b * HH + c0];
        float4 p1 = *(const float4*)&pacc[(size_t)b * HH + c0 + 4];
        a[0] += p0.x; a[1] += p0.y; a[2] += p0.z; a[3] += p0.w;
        a[4] += p1.x; a[5] += p1.y; a[6] += p1.z; a[7] += p1.w;
    }
#pragma unroll
    for (int j = 0; j < 8; ++j)
#pragma unroll
        for (int o = 32; o; o >>= 1) a[j] += __shfl_xor(a[j], o, 64);
    if (lane == 0) {
#pragma unroll
        for (int j = 0; j < 8; ++j) sh[wv * 8 + j] = a[j];
    }
    __syncthreads();
    if (tid < 8) {
        float s2 = 0.f;
        for (int r = 0; r < nw; ++r) s2 += sh[r * 8 + tid];
        out[c0 + tid] = s2 * inv;
    }
}

// ---------- cooperative mega-kernel: 5 syncs/step, atomic combines ----------
__global__ __launch_bounds__(512, 4)
void step_mega(const ushort_t* __restrict__ afeat, const ushort_t* __restrict__ hfeat,
               const ushort_t* __restrict__ Abf,
               const float* __restrict__ w_ih, const float* __restrict__ w_hh,
               const float* __restrict__ b_ih, const float* __restrict__ b_hh,
               const float* __restrict__ hop_wq, const float* __restrict__ attn_wq,
               const float* __restrict__ hop_v, const float* __restrict__ attn_v,
               const float* __restrict__ score_w, const float* __restrict__ score_b,
               const int* __restrict__ mask,
               const float* __restrict__ init_i, const float* __restrict__ init_h,
               const float* __restrict__ init_c,
               float* __restrict__ gates, float* __restrict__ hbuf,
               float* __restrict__ cb0, float* __restrict__ cb1,
               float* __restrict__ qacc, float* __restrict__ xacc,
               float* __restrict__ lh, float* __restrict__ l2,
               float* __restrict__ qw1, float* __restrict__ qw2,
               float* __restrict__ dout) {
    cg::grid_group grid = cg::this_grid();
    __shared__ float sh[4104];      // 8x512 col partials + 8 lsums (A phases)
    const int tid = threadIdx.x;    // 0..511
    const int bid = blockIdx.x;     // 0..511
    const int lane = tid & 63;
    const int wv = tid >> 6;        // 0..7
    const int gwave = bid * 8 + wv; // 0..4095

    for (int s = 0; s < NSTEP; ++s) {
        const float* hin = s ? hbuf : init_h;
        const float* cin = (s == 0) ? init_c : ((s & 1) ? cb0 : cb1);
        float* co        = (s & 1) ? cb1 : cb0;

        // P1: LSTM gates (waves 0..2047, x = xacc/l2 folded as scalar);
        //     block 511 wave 0 emits score(s-1) from the same xacc/l2.
        if (gwave < 4 * HH) {
            const float* wi = w_ih + (size_t)gwave * DD;
            const float* wh = w_hh + (size_t)gwave * HH;
            float sx = 0.f, shh = 0.f;
#pragma unroll
            for (int t = 0; t < 8; ++t) {
                const int k = lane + 64 * t;
                sx  += wi[k] * (s ? xacc[k] : init_i[k]);
                shh += wh[k] * hin[k];
            }
#pragma unroll
            for (int o = 32; o; o >>= 1) {
                sx  += __shfl_xor(sx, o, 64);
                shh += __shfl_xor(shh, o, 64);
            }
            if (lane == 0) {
                const float xs = s ? (1.0f / l2[0]) : 1.0f;
                gates[gwave] = sx * xs + shh + b_ih[gwave] + b_hh[gwave];
            }
        } else if (bid == 511 && wv == 0 && s > 0) {
            float sum = 0.f;
#pragma unroll
            for (int t = 0; t < 8; ++t) {
                const int k = lane + 64 * t;
                sum += xacc[k] * score_w[k];
            }
#pragma unroll
            for (int o = 32; o; o >>= 1) sum += __shfl_xor(sum, o, 64);
            if (lane == 0) dout[s - 1] = sum / l2[0] + score_b[0];
        }
        grid.sync();

        // P2: h,c + qw1 = h @ hop_wq (blocks 0..7); block 8 zeroes qacc,lh
        if (bid < 8) {
            {
                const int j = tid;
                const float ig = gates[j], fg = gates[HH + j];
                const float gg = gates[2 * HH + j], og = gates[3 * HH + j];
                const float si = 1.f / (1.f + __expf(-ig));
                const float sf = 1.f / (1.f + __expf(-fg));
                const float so = 1.f / (1.f + __expf(-og));
                const float cn = sf * cin[j] + si * tanhf(gg);
                const float hn = so * tanhf(cn);
                sh[j] = hn;
                if (bid == 0) { co[j] = cn; hbuf[j] = hn; }
            }
            __syncthreads();
            const int col = bid * 64 + lane;
            float sum = 0.f;
            const int k0 = wv * 64;
#pragma unroll 4
            for (int k = k0; k < k0 + 64; ++k) sum += sh[k] * hop_wq[(size_t)k * HH + col];
            sh[512 + wv * 64 + lane] = sum;
            __syncthreads();
            if (wv == 0) {
                float t2 = 0.f;
#pragma unroll
                for (int r = 0; r < 8; ++r) t2 += sh[512 + r * 64 + lane];
                qw1[col] = t2;
            }
        } else if (bid == 8) {
            qacc[tid] = 0.f;
            if (tid == 0) lh[0] = 0.f;
        }
        grid.sync();

        // P3: hop attention + block-reduce + atomicAdd into qacc,lh
        {
            float acc[8], ls;
            attn_core<true>(hfeat, nullptr, qw1, hop_v, mask, gwave, lane, acc, ls);
#pragma unroll
            for (int j = 0; j < 8; ++j) sh[wv * 512 + lane * 8 + j] = acc[j];
            if (lane == 0) sh[4096 + wv] = ls;
            __syncthreads();
            float csum = 0.f;
#pragma unroll
            for (int r = 0; r < 8; ++r) csum += sh[r * 512 + tid];
            atomicAdd(&qacc[tid], csum);
            if (tid == 0) {
                float lt = 0.f;
#pragma unroll
                for (int r = 0; r < 8; ++r) lt += sh[4096 + r];
                atomicAdd(lh, lt);
            }
        }
        grid.sync();

        // P4: qw2 = (qacc/lh) @ attn_wq (blocks 0..7); block 8 zeroes xacc,l2
        if (bid < 8) {
            const float invl = 1.0f / lh[0];
            sh[tid] = qacc[tid] * invl;
            __syncthreads();
            const int col = bid * 64 + lane;
            float sum = 0.f;
            const int k0 = wv * 64;
#pragma unroll 4
            for (int k = k0; k < k0 + 64; ++k) sum += sh[k] * attn_wq[(size_t)k * HH + col];
            sh[512 + wv * 64 + lane] = sum;
            __syncthreads();
            if (wv == 0) {
                float t2 = 0.f;
#pragma unroll
                for (int r = 0; r < 8; ++r) t2 += sh[512 + r * 64 + lane];
                qw2[col] = t2;
            }
        } else if (bid == 8) {
            xacc[tid] = 0.f;
            if (tid == 0) l2[0] = 0.f;
        }
        grid.sync();

        // P5: final attention + block-reduce + atomicAdd into xacc,l2
        {
            float acc[8], ls;
            attn_core<false>(afeat, Abf, qw2, attn_v, mask, gwave, lane, acc, ls);
#pragma unroll
            for (int j = 0; j < 8; ++j) sh[wv * 512 + lane * 8 + j] = acc[j];
            if (lane == 0) sh[4096 + wv] = ls;
            __syncthreads();
            float csum = 0.f;
#pragma unroll
            for (int r = 0; r < 8; ++r) csum += sh[r * 512 + tid];
            atomicAdd(&xacc[tid], csum);
            if (tid == 0) {
                float lt = 0.f;
#pragma unroll
                for (int r = 0; r < 8; ++r) lt += sh[4096 + r];
                atomicAdd(l2, lt);
            }
        }
        grid.sync();
    }

    // final score (xacc/l2 of step NSTEP-1 live after last sync)
    if (bid == 511 && wv == 0) {
        float sum = 0.f;
#pragma unroll
        for (int t = 0; t < 8; ++t) {
            const int k = lane + 64 * t;
            sum += xacc[k] * score_w[k];
        }
#pragma unroll
        for (int o = 32; o; o >>= 1) sum += __shfl_xor(sum, o, 64);
        if (lane == 0) dout[NSTEP - 1] = sum / l2[0] + score_b[0];
    }
}

// ---------- fallback kernels (r6-proven path) ----------
__global__ __launch_bounds__(256)
void lstm_gates(const float* __restrict__ x, const float* __restrict__ h,
                const float* __restrict__ w_ih, const float* __restrict__ w_hh,
                const float* __restrict__ b_ih, const float* __restrict__ b_hh,
                float* __restrict__ gates) {
    const int wave = (blockIdx.x * 256 + threadIdx.x) >> 6;
    const int lane = threadIdx.x & 63;
    const float* wi = w_ih + (size_t)wave * DD;
    const float* wh = w_hh + (size_t)wave * HH;
    float s = 0.f;
#pragma unroll
    for (int t = 0; t < 8; ++t) {
        int k = lane + 64 * t;
        s += wi[k] * x[k] + wh[k] * h[k];
    }
#pragma unroll
    for (int off = 32; off; off >>= 1) s += __shfl_xor(s, off, 64);
    if (lane == 0) gates[wave] = s + b_ih[wave] + b_hh[wave];
}

__global__ __launch_bounds__(512)
void lstm_tail(const float* __restrict__ gates, const float* __restrict__ cin,
               float* __restrict__ cout, float* __restrict__ hout,
               const float* __restrict__ Wq, float* __restrict__ qwout) {
    __shared__ float hs[HH];
    __shared__ float red[8][64];
    const int j = threadIdx.x;
    {
        float ig = gates[j], fg = gates[HH + j], gg = gates[2 * HH + j], og = gates[3 * HH + j];
        float si = 1.f / (1.f + __expf(-ig));
        float sf = 1.f / (1.f + __expf(-fg));
        float so = 1.f / (1.f + __expf(-og));
        float cn = sf * cin[j] + si * tanhf(gg);
        float hn = so * tanhf(cn);
        hs[j] = hn;
        if (blockIdx.x == 0) { cout[j] = cn; hout[j] = hn; }
    }
    __syncthreads();
    const int lane = threadIdx.x & 63, wv = threadIdx.x >> 6;
    const int col = blockIdx.x * 64 + lane;
    float s = 0.f;
    const int k0 = wv * 64;
#pragma unroll 4
    for (int k = k0; k < k0 + 64; ++k) s += hs[k] * Wq[(size_t)k * HH + col];
    red[wv][lane] = s;
    __syncthreads();
    if (wv == 0) {
        float t = 0.f;
#pragma unroll
        for (int r = 0; r < 8; ++r) t += red[r][lane];
        qwout[col] = t;
    }
}

__global__ __launch_bounds__(512)
void vecmat512(const float* __restrict__ q, const float* __restrict__ W,
               float* __restrict__ out) {
    __shared__ float red[8][64];
    const int lane = threadIdx.x & 63, wv = threadIdx.x >> 6;
    const int j = blockIdx.x * 64 + lane;
    float s = 0.f;
    const int k0 = wv * 64;
#pragma unroll 4
    for (int k = k0; k < k0 + 64; ++k) s += q[k] * W[(size_t)k * HH + j];
    red[wv][lane] = s;
    __syncthreads();
    if (wv == 0) {
        float t = 0.f;
#pragma unroll
        for (int r = 0; r < 8; ++r) t += red[r][lane];
        out[j] = t;
    }
}

template<bool HOP>
__global__ __launch_bounds__(256)
void attn_partial_k(const ushort_t* __restrict__ feat, const ushort_t* __restrict__ mem,
                    const float* __restrict__ qw, const float* __restrict__ v,
                    const int* __restrict__ mask,
                    float* __restrict__ pl, float* __restrict__ pacc) {
    const int wave = blockIdx.x * 4 + (threadIdx.x >> 6);
    const int lane = threadIdx.x & 63;
    float acc[8], ls;
    attn_core<HOP>(feat, mem, qw, v, mask, wave, lane, acc, ls);
    const size_t base = (size_t)wave * HH + lane * 8;
    *(float4*)&pacc[base]     = make_float4(acc[0], acc[1], acc[2], acc[3]);
    *(float4*)&pacc[base + 4] = make_float4(acc[4], acc[5], acc[6], acc[7]);
    if (lane == 0) pl[wave] = ls;
}

__global__ __launch_bounds__(256)
void attn_combine_k(const float* __restrict__ pl, const float* __restrict__ pacc,
                    float* __restrict__ out) {
    __shared__ float sh[64];
    combine_body(pl, pacc, out, sh, blockIdx.x * 8, threadIdx.x, 256);
}

__global__ void score_k(const float* __restrict__ x, const float* __restrict__ sw,
                        const float* __restrict__ sb, float* __restrict__ out) {
    const int lane = threadIdx.x;   // 64
    float s = 0.f;
#pragma unroll
    for (int t = 0; t < 8; ++t) {
        int k = lane + 64 * t;
        s += x[k] * sw[k];
    }
#pragma unroll
    for (int off = 32; off; off >>= 1) s += __shfl_xor(s, off, 64);
    if (lane == 0) out[0] = s + sb[0];
}

// ---------- launcher ----------
extern "C" void kernel_launch(void* const* d_in, const int* in_sizes, int n_in,
                              void* d_out, int out_size, void* d_ws, size_t ws_size,
                              hipStream_t stream) {
    (void)in_sizes; (void)n_in; (void)out_size; (void)ws_size;
    const float* attn_mem = (const float*)d_in[0];
    const float* attn_wm  = (const float*)d_in[1];
    const float* attn_wq  = (const float*)d_in[2];
    const float* attn_v   = (const float*)d_in[3];
    const float* hop_wm   = (const float*)d_in[4];
    const float* hop_wq   = (const float*)d_in[5];
    const float* hop_v    = (const float*)d_in[6];
    const float* init_i   = (const float*)d_in[7];
    const float* init_h   = (const float*)d_in[8];
    const float* init_c   = (const float*)d_in[9];
    const float* w_ih     = (const float*)d_in[10];
    const float* w_hh     = (const float*)d_in[11];
    const float* b_ih     = (const float*)d_in[12];
    const float* b_hh     = (const float*)d_in[13];
    const float* score_w  = (const float*)d_in[14];
    const float* score_b  = (const float*)d_in[15];
    const int*   mask     = (const int*)d_in[16];
    float* dout = (float*)d_out;

    size_t off = 0;
    char* base = (char*)d_ws;
    auto carve = [&](size_t bytes) -> char* {
        char* p = base + off;
        off += (bytes + 255) & ~(size_t)255;
        return p;
    };
    ushort_t* Abf   = (ushort_t*)carve((size_t)NN * DD * 2);
    ushort_t* WT0   = (ushort_t*)carve((size_t)DD * HH * 2);
    ushort_t* WT1   = (ushort_t*)carve((size_t)DD * HH * 2);
    ushort_t* afeat = (ushort_t*)carve((size_t)NN * HH * 2);
    ushort_t* hfeat = (ushort_t*)carve((size_t)NN * HH * 2);
    float* pacc  = (float*)carve((size_t)NWAVE * HH * 4);
    float* pl    = (float*)carve((size_t)NWAVE * 4);
    float* gates = (float*)carve(4 * HH * 4);
    float* hbuf  = (float*)carve(HH * 4);
    float* cb0   = (float*)carve(HH * 4);
    float* cb1   = (float*)carve(HH * 4);
    float* qbuf  = (float*)carve(HH * 4);
    float* qwbuf = (float*)carve(HH * 4);
    float* xbuf  = (float*)carve(DD * 4);
    float* qacc  = (float*)carve(HH * 4);
    float* xacc  = (float*)carve(HH * 4);
    float* qw1   = (float*)carve(HH * 4);
    float* qw2   = (float*)carve(HH * 4);
    float* lh    = (float*)carve(256);
    float* l2    = (float*)carve(256);

    conv_bf16<<<(NN * DD / 8) / 256, 256, 0, stream>>>(attn_mem, Abf);
    conv_wt<<<dim3(128, 2), 256, 0, stream>>>(attn_wm, hop_wm, WT0, WT1);
    gemm_mfma<<<4096, 256, 0, stream>>>(Abf, WT0, WT1,
        (__hip_bfloat16*)afeat, (__hip_bfloat16*)hfeat);

    // host-side occupancy check (deterministic, graph-capture-safe)
    int dev = 0;
    (void)hipGetDevice(&dev);
    int numCU = 0;
    (void)hipDeviceGetAttribute(&numCU, hipDeviceAttributeMultiprocessorCount, dev);
    int maxBlk = 0;
    (void)hipOccupancyMaxActiveBlocksPerMultiprocessor(&maxBlk, (const void*)step_mega, 512, 0);
    bool coop_ok = (maxBlk > 0) && ((long)maxBlk * (long)numCU >= MEGA_BLOCKS);

    if (coop_ok) {
        const ushort_t* k_afeat = afeat;
        const ushort_t* k_hfeat = hfeat;
        const ushort_t* k_Abf   = Abf;
        void* args[] = {
            (void*)&k_afeat, (void*)&k_hfeat, (void*)&k_Abf,
            (void*)&w_ih, (void*)&w_hh, (void*)&b_ih, (void*)&b_hh,
            (void*)&hop_wq, (void*)&attn_wq, (void*)&hop_v, (void*)&attn_v,
            (void*)&score_w, (void*)&score_b, (void*)&mask,
            (void*)&init_i, (void*)&init_h, (void*)&init_c,
            (void*)&gates, (void*)&hbuf, (void*)&cb0, (void*)&cb1,
            (void*)&qacc, (void*)&xacc, (void*)&lh, (void*)&l2,
            (void*)&qw1, (void*)&qw2, (void*)&dout
        };
        coop_ok = (hipLaunchCooperativeKernel((void*)step_mega, dim3(MEGA_BLOCKS),
                                              dim3(512), args, 0, stream) == hipSuccess);
    }
    if (!coop_ok) {
        for (int s = 0; s < NSTEP; ++s) {
            const float* x   = s ? xbuf : init_i;
            const float* hin = s ? hbuf : init_h;
            const float* cin = s == 0 ? init_c : (s & 1 ? cb0 : cb1);
            float* cout      = (s & 1) ? cb1 : cb0;
            lstm_gates<<<512, 256, 0, stream>>>(x, hin, w_ih, w_hh, b_ih, b_hh, gates);
            lstm_tail<<<8, 512, 0, stream>>>(gates, cin, cout, hbuf, hop_wq, qwbuf);
            attn_partial_k<true><<<ABLOCKS, 256, 0, stream>>>(hfeat, nullptr, qwbuf, hop_v, mask, pl, pacc);
            attn_combine_k<<<64, 256, 0, stream>>>(pl, pacc, qbuf);
            vecmat512<<<8, 512, 0, stream>>>(qbuf, attn_wq, qwbuf);
            attn_partial_k<false><<<ABLOCKS, 256, 0, stream>>>(afeat, Abf, qwbuf, attn_v, mask, pl, pacc);
            attn_combine_k<<<64, 256, 0, stream>>>(pl, pacc, xbuf);
            score_k<<<1, 64, 0, stream>>>(xbuf, score_w, score_b, dout + s);
        }
    }
}

// Round 10
// 526.569 us; speedup vs baseline: 1.0002x; 1.0002x over previous
//
#include <hip/hip_runtime.h>
#include <hip/hip_bf16.h>
#include <hip/hip_cooperative_groups.h>

namespace cg = cooperative_groups;

#define NN 65536
#define DD 512
#define HH 512
#define NSTEP 4
#define NEG_INFF -100000000.0f

#define RPW 16                 // rows per wave in attention phases
#define NWAVE 4096             // 4096 waves x 16 rows = 65536
#define ABLOCKS 1024           // fallback attn grid (256-thread blocks)
#define MEGA_BLOCKS 512        // cooperative grid (512-thread blocks)

typedef unsigned short ushort_t;
typedef __attribute__((ext_vector_type(8))) short bf16x8;
typedef __attribute__((ext_vector_type(4))) float f32x4;

// ---------- helpers ----------
__device__ __forceinline__ float bflo(unsigned u) {
    union { unsigned i; float f; } v; v.i = u << 16; return v.f;
}
__device__ __forceinline__ float bfhi(unsigned u) {
    union { unsigned i; float f; } v; v.i = u & 0xffff0000u; return v.f;
}
__device__ __forceinline__ float fast_tanh(float x) {
    float e = __expf(2.0f * x);
    return 1.0f - 2.0f * __builtin_amdgcn_rcpf(e + 1.0f);
}

#define GL2LDS(g, l) __builtin_amdgcn_global_load_lds( \
    (const __attribute__((address_space(1))) unsigned int*)(g), \
    (__attribute__((address_space(3))) unsigned int*)(l), 16, 0, 0)

// ---------- f32 -> bf16 convert (attn_mem) ----------
__global__ __launch_bounds__(256)
void conv_bf16(const float* __restrict__ in, ushort_t* __restrict__ out) {
    const int i = blockIdx.x * 256 + threadIdx.x;
    const size_t base = (size_t)i * 8;
    float4 a = *(const float4*)&in[base];
    float4 b = *(const float4*)&in[base + 4];
    union { __hip_bfloat16 h[8]; uint4 u; } t;
    t.h[0] = __float2bfloat16(a.x); t.h[1] = __float2bfloat16(a.y);
    t.h[2] = __float2bfloat16(a.z); t.h[3] = __float2bfloat16(a.w);
    t.h[4] = __float2bfloat16(b.x); t.h[5] = __float2bfloat16(b.y);
    t.h[6] = __float2bfloat16(b.z); t.h[7] = __float2bfloat16(b.w);
    *(uint4*)&out[base] = t.u;
}

// ---------- weight transpose + convert: WT[n][k] = bf16(W[k][n]) ----------
__global__ __launch_bounds__(256)
void conv_wt(const float* __restrict__ W0, const float* __restrict__ W1,
             ushort_t* __restrict__ T0, ushort_t* __restrict__ T1) {
    const float* W = blockIdx.y ? W1 : W0;
    ushort_t* T = blockIdx.y ? T1 : T0;
    const int n = blockIdx.x * 4 + (threadIdx.x >> 6);
    const int k0 = (threadIdx.x & 63) * 8;
    union { __hip_bfloat16 h[8]; uint4 u; } t;
#pragma unroll
    for (int i = 0; i < 8; ++i)
        t.h[i] = __float2bfloat16(W[(size_t)(k0 + i) * HH + n]);
    *(uint4*)&T[(size_t)n * DD + k0] = t.u;
}

// ---------- MFMA GEMM: XCD-locality grid + 2-phase LDS double-buffer ----------
#define TM 128
#define TK 32
#define NT (DD / TK)   // 16 K-steps
__global__ __launch_bounds__(256)
void gemm_mfma(const ushort_t* __restrict__ A,
               const ushort_t* __restrict__ WT0, const ushort_t* __restrict__ WT1,
               __hip_bfloat16* __restrict__ C0, __hip_bfloat16* __restrict__ C1) {
    __shared__ ushort_t As[2][TM * TK];
    __shared__ ushort_t Bs[2][TM * TK];
    const int L = blockIdx.x;
    const int xcd = L & 7;
    const int slot = L >> 3;
    const int mt = xcd * 64 + (slot >> 3);
    const int my = slot & 7;
    const ushort_t* WT = (my < 4) ? WT0 : WT1;
    __hip_bfloat16* Cp = (my < 4) ? C0 : C1;
    const int bn = (my & 3) * TM;
    const int bm = mt * TM;
    const int tid = threadIdx.x;
    const int lane = tid & 63;
    const int wid = tid >> 6;
    const int wr = (wid >> 1) * 64;
    const int wc = (wid & 1) * 64;
    const int l15 = lane & 15;
    const int srow = lane >> 2;
    const int ske = (((lane & 3) ^ ((lane >> 3) & 3)) * 8);
    const int koff = (((lane >> 4) ^ ((l15 >> 1) & 3)) << 3);

    const ushort_t* Abase = A + (size_t)bm * DD;
    const ushort_t* Bbase = WT + (size_t)bn * DD;

    auto stage = [&](int b, int k0) {
#pragma unroll
        for (int u = 0; u < 2; ++u) {
            const int g = u * 4 + wid;
            const int row = g * 16 + srow;
            GL2LDS(Abase + (size_t)row * DD + k0 + ske, &As[b][g * 512]);
            GL2LDS(Bbase + (size_t)row * DD + k0 + ske, &Bs[b][g * 512]);
        }
    };

    const f32x4 zero = {0.f, 0.f, 0.f, 0.f};
    f32x4 acc[4][4];
#pragma unroll
    for (int m = 0; m < 4; ++m)
#pragma unroll
        for (int n = 0; n < 4; ++n) acc[m][n] = zero;

    stage(0, 0);
    stage(1, TK);
    __builtin_amdgcn_sched_barrier(0);

    for (int t = 0; t < NT; ++t) {
        const int cur = t & 1;
        if (t + 1 < NT) asm volatile("s_waitcnt vmcnt(4)" ::: "memory");
        else            asm volatile("s_waitcnt vmcnt(0)" ::: "memory");
        __builtin_amdgcn_sched_barrier(0);
        __builtin_amdgcn_s_barrier();
        __builtin_amdgcn_sched_barrier(0);

        bf16x8 af[4], bfr[4];
#pragma unroll
        for (int m = 0; m < 4; ++m)
            af[m] = *(const bf16x8*)(&As[cur][(wr + m * 16 + l15) * TK + koff]);
#pragma unroll
        for (int n = 0; n < 4; ++n)
            bfr[n] = *(const bf16x8*)(&Bs[cur][(wc + n * 16 + l15) * TK + koff]);
#pragma unroll
        for (int m = 0; m < 4; ++m)
#pragma unroll
            for (int n = 0; n < 4; ++n)
                acc[m][n] = __builtin_amdgcn_mfma_f32_16x16x32_bf16(af[m], bfr[n], acc[m][n], 0, 0, 0);

        asm volatile("s_waitcnt lgkmcnt(0)" ::: "memory");
        __builtin_amdgcn_sched_barrier(0);
        __builtin_amdgcn_s_barrier();
        __builtin_amdgcn_sched_barrier(0);
        if (t + 2 < NT) stage(cur, (t + 2) * TK);
        __builtin_amdgcn_sched_barrier(0);
    }

    const int r0 = (lane >> 4) * 4;
#pragma unroll
    for (int m = 0; m < 4; ++m) {
#pragma unroll
        for (int n = 0; n < 4; ++n) {
            const f32x4 vv = acc[m][n];
            const size_t cb = (size_t)(bm + wr + m * 16 + r0) * HH + bn + wc + n * 16 + l15;
#pragma unroll
            for (int r = 0; r < 4; ++r)
                Cp[cb + (size_t)r * HH] = __float2bfloat16(vv[r]);
        }
    }
}

// ---------- attention core: 4-deep NAMED-register prefetch ring ----------
template<bool HOP>
__device__ __forceinline__
void attn_core(const ushort_t* __restrict__ feat, const ushort_t* __restrict__ mem,
               const float* __restrict__ qw, const float* __restrict__ v,
               const int* __restrict__ mask, int wave, int lane,
               float acc[8], float& lsum) {
    float qv[8], vv[8];
    {
        float4 q0 = *(const float4*)&qw[lane * 8];
        float4 q1 = *(const float4*)&qw[lane * 8 + 4];
        qv[0] = q0.x; qv[1] = q0.y; qv[2] = q0.z; qv[3] = q0.w;
        qv[4] = q1.x; qv[5] = q1.y; qv[6] = q1.z; qv[7] = q1.w;
        float4 v0 = *(const float4*)&v[lane * 8];
        float4 v1 = *(const float4*)&v[lane * 8 + 4];
        vv[0] = v0.x; vv[1] = v0.y; vv[2] = v0.z; vv[3] = v0.w;
        vv[4] = v1.x; vv[5] = v1.y; vv[6] = v1.z; vv[7] = v1.w;
    }
    float C = 0.f;
#pragma unroll
    for (int j = 0; j < 8; ++j) C += fabsf(vv[j]);
#pragma unroll
    for (int o = 32; o; o >>= 1) C += __shfl_xor(C, o, 64);

    lsum = 0.f;
#pragma unroll
    for (int j = 0; j < 8; ++j) acc[j] = 0.f;
    const int row0 = wave * RPW;
    const ushort_t* fp = feat + (size_t)row0 * HH + lane * 8;
    const ushort_t* mp = mem + (size_t)row0 * DD + lane * 8;

    auto body = [&](uint4 fc, uint4 mc, int row) {
        float f[8];
        f[0] = bflo(fc.x); f[1] = bfhi(fc.x); f[2] = bflo(fc.y); f[3] = bfhi(fc.y);
        f[4] = bflo(fc.z); f[5] = bfhi(fc.z); f[6] = bflo(fc.w); f[7] = bfhi(fc.w);
        float mv[8];
        if (!HOP) {
            mv[0] = bflo(mc.x); mv[1] = bfhi(mc.x); mv[2] = bflo(mc.y); mv[3] = bfhi(mc.y);
            mv[4] = bflo(mc.z); mv[5] = bfhi(mc.z); mv[6] = bflo(mc.w); mv[7] = bfhi(mc.w);
        } else {
#pragma unroll
            for (int j = 0; j < 8; ++j) mv[j] = f[j];
        }
        float d = 0.f;
#pragma unroll
        for (int j = 0; j < 8; ++j) d += fast_tanh(f[j] + qv[j]) * vv[j];
#pragma unroll
        for (int o = 32; o; o >>= 1) d += __shfl_xor(d, o, 64);
        const float sc = d - C + (mask[row] ? 0.f : NEG_INFF);
        const float p = __expf(sc);
        lsum += p;
#pragma unroll
        for (int j = 0; j < 8; ++j) acc[j] += p * mv[j];
    };

    // 4-deep ring in NAMED registers (no array indexing -> no scratch)
    uint4 f0 = *(const uint4*)(fp);
    uint4 f1 = *(const uint4*)(fp + HH);
    uint4 f2 = *(const uint4*)(fp + 2 * HH);
    uint4 f3 = *(const uint4*)(fp + 3 * HH);
    uint4 m0, m1, m2, m3;
    if (!HOP) {
        m0 = *(const uint4*)(mp);
        m1 = *(const uint4*)(mp + DD);
        m2 = *(const uint4*)(mp + 2 * DD);
        m3 = *(const uint4*)(mp + 3 * DD);
    }
#pragma unroll
    for (int rb = 0; rb < RPW / 4; ++rb) {
        const int rbase = row0 + rb * 4;
        body(f0, m0, rbase + 0);
        if (rb < RPW / 4 - 1) {
            f0 = *(const uint4*)(fp + (size_t)(rb * 4 + 4) * HH);
            if (!HOP) m0 = *(const uint4*)(mp + (size_t)(rb * 4 + 4) * DD);
        }
        body(f1, m1, rbase + 1);
        if (rb < RPW / 4 - 1) {
            f1 = *(const uint4*)(fp + (size_t)(rb * 4 + 5) * HH);
            if (!HOP) m1 = *(const uint4*)(mp + (size_t)(rb * 4 + 5) * DD);
        }
        body(f2, m2, rbase + 2);
        if (rb < RPW / 4 - 1) {
            f2 = *(const uint4*)(fp + (size_t)(rb * 4 + 6) * HH);
            if (!HOP) m2 = *(const uint4*)(mp + (size_t)(rb * 4 + 6) * DD);
        }
        body(f3, m3, rbase + 3);
        if (rb < RPW / 4 - 1) {
            f3 = *(const uint4*)(fp + (size_t)(rb * 4 + 7) * HH);
            if (!HOP) m3 = *(const uint4*)(mp + (size_t)(rb * 4 + 7) * DD);
        }
    }
}

// ---------- fallback combine (r6-proven, over NWAVE per-wave partials) ----------
__device__ __forceinline__
void combine_body(const float* __restrict__ pl, const float* __restrict__ pacc,
                  float* __restrict__ out, float* __restrict__ sh,
                  int c0, int tid, int nthr) {
    const int lane = tid & 63, wv = tid >> 6;
    const int nw = nthr >> 6;
    float lg = 0.f;
    for (int b = tid; b < NWAVE; b += nthr) lg += pl[b];
#pragma unroll
    for (int o = 32; o; o >>= 1) lg += __shfl_xor(lg, o, 64);
    if (lane == 0) sh[wv] = lg;
    __syncthreads();
    float lt = 0.f;
    for (int r = 0; r < nw; ++r) lt += sh[r];
    const float inv = 1.0f / lt;
    __syncthreads();
    float a[8];
#pragma unroll
    for (int j = 0; j < 8; ++j) a[j] = 0.f;
    for (int b = tid; b < NWAVE; b += nthr) {
        float4 p0 = *(const float4*)&pacc[(size_t)b * HH + c0];
        float4 p1 = *(const float4*)&pacc[(size_t)b * HH + c0 + 4];
        a[0] += p0.x; a[1] += p0.y; a[2] += p0.z; a[3] += p0.w;
        a[4] += p1.x; a[5] += p1.y; a[6] += p1.z; a[7] += p1.w;
    }
#pragma unroll
    for (int j = 0; j < 8; ++j)
#pragma unroll
        for (int o = 32; o; o >>= 1) a[j] += __shfl_xor(a[j], o, 64);
    if (lane == 0) {
#pragma unroll
        for (int j = 0; j < 8; ++j) sh[wv * 8 + j] = a[j];
    }
    __syncthreads();
    if (tid < 8) {
        float s2 = 0.f;
        for (int r = 0; r < nw; ++r) s2 += sh[r * 8 + tid];
        out[c0 + tid] = s2 * inv;
    }
}

// ---------- mega combine: over 512 per-block partials (1 MB), 512 threads ----------
__device__ __forceinline__
void combine2(const float* __restrict__ pl2, const float* __restrict__ pacc2,
              float* __restrict__ out, float* __restrict__ sh, int c0, int tid) {
    const int lane = tid & 63, wv = tid >> 6;
    float lg = pl2[tid];   // 512 threads, 512 entries
#pragma unroll
    for (int o = 32; o; o >>= 1) lg += __shfl_xor(lg, o, 64);
    if (lane == 0) sh[wv] = lg;
    __syncthreads();
    float lt = 0.f;
#pragma unroll
    for (int r = 0; r < 8; ++r) lt += sh[r];
    const float inv = 1.0f / lt;
    __syncthreads();
    float a[8];
    {
        const float4 p0 = *(const float4*)&pacc2[(size_t)tid * HH + c0];
        const float4 p1 = *(const float4*)&pacc2[(size_t)tid * HH + c0 + 4];
        a[0] = p0.x; a[1] = p0.y; a[2] = p0.z; a[3] = p0.w;
        a[4] = p1.x; a[5] = p1.y; a[6] = p1.z; a[7] = p1.w;
    }
#pragma unroll
    for (int j = 0; j < 8; ++j)
#pragma unroll
        for (int o = 32; o; o >>= 1) a[j] += __shfl_xor(a[j], o, 64);
    if (lane == 0) {
#pragma unroll
        for (int j = 0; j < 8; ++j) sh[wv * 8 + j] = a[j];
    }
    __syncthreads();
    if (tid < 8) {
        float s2 = 0.f;
#pragma unroll
        for (int r = 0; r < 8; ++r) s2 += sh[r * 8 + tid];
        out[c0 + tid] = s2 * inv;
    }
}

// ---------- cooperative mega-kernel (r8 phase graph, 7 syncs/step) ----------
__global__ __launch_bounds__(512, 2)
void step_mega(const ushort_t* __restrict__ afeat, const ushort_t* __restrict__ hfeat,
               const ushort_t* __restrict__ Abf,
               const float* __restrict__ w_ih, const float* __restrict__ w_hh,
               const float* __restrict__ b_ih, const float* __restrict__ b_hh,
               const float* __restrict__ hop_wq, const float* __restrict__ attn_wq,
               const float* __restrict__ hop_v, const float* __restrict__ attn_v,
               const float* __restrict__ score_w, const float* __restrict__ score_b,
               const int* __restrict__ mask,
               const float* __restrict__ init_i, const float* __restrict__ init_h,
               const float* __restrict__ init_c,
               float* __restrict__ gates, float* __restrict__ hbuf,
               float* __restrict__ cb0, float* __restrict__ cb1,
               float* __restrict__ qbuf, float* __restrict__ qwbuf,
               float* __restrict__ xbuf,
               float* __restrict__ pl2, float* __restrict__ pacc2,
               float* __restrict__ dout) {
    cg::grid_group grid = cg::this_grid();
    __shared__ float sh[4104];      // [8][512] acc partials + 8 lsums
    const int tid = threadIdx.x;    // 0..511
    const int bid = blockIdx.x;     // 0..511
    const int lane = tid & 63;
    const int wv = tid >> 6;        // 0..7
    const int gwave = bid * 8 + wv; // 0..4095

    for (int s = 0; s < NSTEP; ++s) {
        const float* x   = s ? xbuf : init_i;
        const float* hin = s ? hbuf : init_h;
        const float* cin = (s == 0) ? init_c : ((s & 1) ? cb0 : cb1);
        float* co        = (s & 1) ? cb1 : cb0;

        // --- L1: LSTM gates (waves 0..2047)
        if (gwave < 4 * HH) {
            const float* wi = w_ih + (size_t)gwave * DD;
            const float* wh = w_hh + (size_t)gwave * HH;
            float sum = 0.f;
#pragma unroll
            for (int t = 0; t < 8; ++t) {
                const int k = lane + 64 * t;
                sum += wi[k] * x[k] + wh[k] * hin[k];
            }
#pragma unroll
            for (int o = 32; o; o >>= 1) sum += __shfl_xor(sum, o, 64);
            if (lane == 0) gates[gwave] = sum + b_ih[gwave] + b_hh[gwave];
        }
        grid.sync();

        // --- L2: h,c update + qw_hop = h @ hop_wq (blocks 0..7)
        if (bid < 8) {
            {
                const int j = tid;
                const float ig = gates[j], fg = gates[HH + j];
                const float gg = gates[2 * HH + j], og = gates[3 * HH + j];
                const float si = 1.f / (1.f + __expf(-ig));
                const float sf = 1.f / (1.f + __expf(-fg));
                const float so = 1.f / (1.f + __expf(-og));
                const float cn = sf * cin[j] + si * tanhf(gg);
                const float hn = so * tanhf(cn);
                sh[j] = hn;
                if (bid == 0) { co[j] = cn; hbuf[j] = hn; }
            }
            __syncthreads();
            const int col = bid * 64 + lane;
            float sum = 0.f;
            const int k0 = wv * 64;
#pragma unroll 4
            for (int k = k0; k < k0 + 64; ++k) sum += sh[k] * hop_wq[(size_t)k * HH + col];
            sh[512 + wv * 64 + lane] = sum;
            __syncthreads();
            if (wv == 0) {
                float t2 = 0.f;
#pragma unroll
                for (int r = 0; r < 8; ++r) t2 += sh[512 + r * 64 + lane];
                qwbuf[col] = t2;
            }
        }
        grid.sync();

        // --- A1: hop attention + block-level LDS reduce -> pacc2[bid], pl2[bid]
        {
            float acc[8], ls;
            attn_core<true>(hfeat, nullptr, qwbuf, hop_v, mask, gwave, lane, acc, ls);
#pragma unroll
            for (int j = 0; j < 8; ++j) sh[wv * 512 + lane * 8 + j] = acc[j];
            if (lane == 0) sh[4096 + wv] = ls;
            __syncthreads();
            float csum = 0.f;
#pragma unroll
            for (int r = 0; r < 8; ++r) csum += sh[r * 512 + tid];
            pacc2[(size_t)bid * HH + tid] = csum;
            if (tid == 0) {
                float lt = 0.f;
#pragma unroll
                for (int r = 0; r < 8; ++r) lt += sh[4096 + r];
                pl2[bid] = lt;
            }
        }
        grid.sync();

        // --- C1: combine -> qbuf (blocks 0..63)
        if (bid < 64) combine2(pl2, pacc2, qbuf, sh, bid * 8, tid);
        grid.sync();

        // --- V: qw2 = qbuf @ attn_wq (blocks 0..7)
        if (bid < 8) {
            sh[tid] = qbuf[tid];
            __syncthreads();
            const int col = bid * 64 + lane;
            float sum = 0.f;
            const int k0 = wv * 64;
#pragma unroll 4
            for (int k = k0; k < k0 + 64; ++k) sum += sh[k] * attn_wq[(size_t)k * HH + col];
            sh[512 + wv * 64 + lane] = sum;
            __syncthreads();
            if (wv == 0) {
                float t2 = 0.f;
#pragma unroll
                for (int r = 0; r < 8; ++r) t2 += sh[512 + r * 64 + lane];
                qwbuf[col] = t2;
            }
        }
        grid.sync();

        // --- A2: final attention + block reduce -> pacc2, pl2
        {
            float acc[8], ls;
            attn_core<false>(afeat, Abf, qwbuf, attn_v, mask, gwave, lane, acc, ls);
#pragma unroll
            for (int j = 0; j < 8; ++j) sh[wv * 512 + lane * 8 + j] = acc[j];
            if (lane == 0) sh[4096 + wv] = ls;
            __syncthreads();
            float csum = 0.f;
#pragma unroll
            for (int r = 0; r < 8; ++r) csum += sh[r * 512 + tid];
            pacc2[(size_t)bid * HH + tid] = csum;
            if (tid == 0) {
                float lt = 0.f;
#pragma unroll
                for (int r = 0; r < 8; ++r) lt += sh[4096 + r];
                pl2[bid] = lt;
            }
        }
        grid.sync();

        // --- C2: combine -> xbuf (blocks 0..63)
        if (bid < 64) combine2(pl2, pacc2, xbuf, sh, bid * 8, tid);
        grid.sync();

        // --- S: score (block 0, wave 0); next L1 writes only gates (disjoint)
        if (bid == 0 && wv == 0) {
            float sum = 0.f;
#pragma unroll
            for (int t = 0; t < 8; ++t) {
                const int k = lane + 64 * t;
                sum += xbuf[k] * score_w[k];
            }
#pragma unroll
            for (int o = 32; o; o >>= 1) sum += __shfl_xor(sum, o, 64);
            if (lane == 0) dout[s] = sum + score_b[0];
        }
    }
}

// ---------- fallback kernels (r6-proven path) ----------
__global__ __launch_bounds__(256)
void lstm_gates(const float* __restrict__ x, const float* __restrict__ h,
                const float* __restrict__ w_ih, const float* __restrict__ w_hh,
                const float* __restrict__ b_ih, const float* __restrict__ b_hh,
                float* __restrict__ gates) {
    const int wave = (blockIdx.x * 256 + threadIdx.x) >> 6;
    const int lane = threadIdx.x & 63;
    const float* wi = w_ih + (size_t)wave * DD;
    const float* wh = w_hh + (size_t)wave * HH;
    float s = 0.f;
#pragma unroll
    for (int t = 0; t < 8; ++t) {
        int k = lane + 64 * t;
        s += wi[k] * x[k] + wh[k] * h[k];
    }
#pragma unroll
    for (int off = 32; off; off >>= 1) s += __shfl_xor(s, off, 64);
    if (lane == 0) gates[wave] = s + b_ih[wave] + b_hh[wave];
}

__global__ __launch_bounds__(512)
void lstm_tail(const float* __restrict__ gates, const float* __restrict__ cin,
               float* __restrict__ cout, float* __restrict__ hout,
               const float* __restrict__ Wq, float* __restrict__ qwout) {
    __shared__ float hs[HH];
    __shared__ float red[8][64];
    const int j = threadIdx.x;
    {
        float ig = gates[j], fg = gates[HH + j], gg = gates[2 * HH + j], og = gates[3 * HH + j];
        float si = 1.f / (1.f + __expf(-ig));
        float sf = 1.f / (1.f + __expf(-fg));
        float so = 1.f / (1.f + __expf(-og));
        float cn = sf * cin[j] + si * tanhf(gg);
        float hn = so * tanhf(cn);
        hs[j] = hn;
        if (blockIdx.x == 0) { cout[j] = cn; hout[j] = hn; }
    }
    __syncthreads();
    const int lane = threadIdx.x & 63, wv = threadIdx.x >> 6;
    const int col = blockIdx.x * 64 + lane;
    float s = 0.f;
    const int k0 = wv * 64;
#pragma unroll 4
    for (int k = k0; k < k0 + 64; ++k) s += hs[k] * Wq[(size_t)k * HH + col];
    red[wv][lane] = s;
    __syncthreads();
    if (wv == 0) {
        float t = 0.f;
#pragma unroll
        for (int r = 0; r < 8; ++r) t += red[r][lane];
        qwout[col] = t;
    }
}

__global__ __launch_bounds__(512)
void vecmat512(const float* __restrict__ q, const float* __restrict__ W,
               float* __restrict__ out) {
    __shared__ float red[8][64];
    const int lane = threadIdx.x & 63, wv = threadIdx.x >> 6;
    const int j = blockIdx.x * 64 + lane;
    float s = 0.f;
    const int k0 = wv * 64;
#pragma unroll 4
    for (int k = k0; k < k0 + 64; ++k) s += q[k] * W[(size_t)k * HH + j];
    red[wv][lane] = s;
    __syncthreads();
    if (wv == 0) {
        float t = 0.f;
#pragma unroll
        for (int r = 0; r < 8; ++r) t += red[r][lane];
        out[j] = t;
    }
}

template<bool HOP>
__global__ __launch_bounds__(256)
void attn_partial_k(const ushort_t* __restrict__ feat, const ushort_t* __restrict__ mem,
                    const float* __restrict__ qw, const float* __restrict__ v,
                    const int* __restrict__ mask,
                    float* __restrict__ pl, float* __restrict__ pacc) {
    const int wave = blockIdx.x * 4 + (threadIdx.x >> 6);
    const int lane = threadIdx.x & 63;
    float acc[8], ls;
    attn_core<HOP>(feat, mem, qw, v, mask, wave, lane, acc, ls);
    const size_t base = (size_t)wave * HH + lane * 8;
    *(float4*)&pacc[base]     = make_float4(acc[0], acc[1], acc[2], acc[3]);
    *(float4*)&pacc[base + 4] = make_float4(acc[4], acc[5], acc[6], acc[7]);
    if (lane == 0) pl[wave] = ls;
}

__global__ __launch_bounds__(256)
void attn_combine_k(const float* __restrict__ pl, const float* __restrict__ pacc,
                    float* __restrict__ out) {
    __shared__ float sh[64];
    combine_body(pl, pacc, out, sh, blockIdx.x * 8, threadIdx.x, 256);
}

__global__ void score_k(const float* __restrict__ x, const float* __restrict__ sw,
                        const float* __restrict__ sb, float* __restrict__ out) {
    const int lane = threadIdx.x;   // 64
    float s = 0.f;
#pragma unroll
    for (int t = 0; t < 8; ++t) {
        int k = lane + 64 * t;
        s += x[k] * sw[k];
    }
#pragma unroll
    for (int off = 32; off; off >>= 1) s += __shfl_xor(s, off, 64);
    if (lane == 0) out[0] = s + sb[0];
}

// ---------- launcher ----------
extern "C" void kernel_launch(void* const* d_in, const int* in_sizes, int n_in,
                              void* d_out, int out_size, void* d_ws, size_t ws_size,
                              hipStream_t stream) {
    (void)in_sizes; (void)n_in; (void)out_size; (void)ws_size;
    const float* attn_mem = (const float*)d_in[0];
    const float* attn_wm  = (const float*)d_in[1];
    const float* attn_wq  = (const float*)d_in[2];
    const float* attn_v   = (const float*)d_in[3];
    const float* hop_wm   = (const float*)d_in[4];
    const float* hop_wq   = (const float*)d_in[5];
    const float* hop_v    = (const float*)d_in[6];
    const float* init_i   = (const float*)d_in[7];
    const float* init_h   = (const float*)d_in[8];
    const float* init_c   = (const float*)d_in[9];
    const float* w_ih     = (const float*)d_in[10];
    const float* w_hh     = (const float*)d_in[11];
    const float* b_ih     = (const float*)d_in[12];
    const float* b_hh     = (const float*)d_in[13];
    const float* score_w  = (const float*)d_in[14];
    const float* score_b  = (const float*)d_in[15];
    const int*   mask     = (const int*)d_in[16];
    float* dout = (float*)d_out;

    size_t off = 0;
    char* base = (char*)d_ws;
    auto carve = [&](size_t bytes) -> char* {
        char* p = base + off;
        off += (bytes + 255) & ~(size_t)255;
        return p;
    };
    ushort_t* Abf   = (ushort_t*)carve((size_t)NN * DD * 2);
    ushort_t* WT0   = (ushort_t*)carve((size_t)DD * HH * 2);
    ushort_t* WT1   = (ushort_t*)carve((size_t)DD * HH * 2);
    ushort_t* afeat = (ushort_t*)carve((size_t)NN * HH * 2);
    ushort_t* hfeat = (ushort_t*)carve((size_t)NN * HH * 2);
    float* pacc  = (float*)carve((size_t)NWAVE * HH * 4);   // fallback
    float* pl    = (float*)carve((size_t)NWAVE * 4);        // fallback
    float* pacc2 = (float*)carve((size_t)MEGA_BLOCKS * HH * 4);
    float* pl2   = (float*)carve((size_t)MEGA_BLOCKS * 4);
    float* gates = (float*)carve(4 * HH * 4);
    float* hbuf  = (float*)carve(HH * 4);
    float* cb0   = (float*)carve(HH * 4);
    float* cb1   = (float*)carve(HH * 4);
    float* qbuf  = (float*)carve(HH * 4);
    float* qwbuf = (float*)carve(HH * 4);
    float* xbuf  = (float*)carve(DD * 4);

    conv_bf16<<<(NN * DD / 8) / 256, 256, 0, stream>>>(attn_mem, Abf);
    conv_wt<<<dim3(128, 2), 256, 0, stream>>>(attn_wm, hop_wm, WT0, WT1);
    gemm_mfma<<<4096, 256, 0, stream>>>(Abf, WT0, WT1,
        (__hip_bfloat16*)afeat, (__hip_bfloat16*)hfeat);

    // host-side occupancy check (deterministic, graph-capture-safe)
    int dev = 0;
    (void)hipGetDevice(&dev);
    int numCU = 0;
    (void)hipDeviceGetAttribute(&numCU, hipDeviceAttributeMultiprocessorCount, dev);
    int maxBlk = 0;
    (void)hipOccupancyMaxActiveBlocksPerMultiprocessor(&maxBlk, (const void*)step_mega, 512, 0);
    bool coop_ok = (maxBlk > 0) && ((long)maxBlk * (long)numCU >= MEGA_BLOCKS);

    if (coop_ok) {
        const ushort_t* k_afeat = afeat;
        const ushort_t* k_hfeat = hfeat;
        const ushort_t* k_Abf   = Abf;
        void* args[] = {
            (void*)&k_afeat, (void*)&k_hfeat, (void*)&k_Abf,
            (void*)&w_ih, (void*)&w_hh, (void*)&b_ih, (void*)&b_hh,
            (void*)&hop_wq, (void*)&attn_wq, (void*)&hop_v, (void*)&attn_v,
            (void*)&score_w, (void*)&score_b, (void*)&mask,
            (void*)&init_i, (void*)&init_h, (void*)&init_c,
            (void*)&gates, (void*)&hbuf, (void*)&cb0, (void*)&cb1,
            (void*)&qbuf, (void*)&qwbuf, (void*)&xbuf,
            (void*)&pl2, (void*)&pacc2, (void*)&dout
        };
        coop_ok = (hipLaunchCooperativeKernel((void*)step_mega, dim3(MEGA_BLOCKS),
                                              dim3(512), args, 0, stream) == hipSuccess);
    }
    if (!coop_ok) {
        for (int s = 0; s < NSTEP; ++s) {
            const float* x   = s ? xbuf : init_i;
            const float* hin = s ? hbuf : init_h;
            const float* cin = s == 0 ? init_c : (s & 1 ? cb0 : cb1);
            float* cout      = (s & 1) ? cb1 : cb0;
            lstm_gates<<<512, 256, 0, stream>>>(x, hin, w_ih, w_hh, b_ih, b_hh, gates);
            lstm_tail<<<8, 512, 0, stream>>>(gates, cin, cout, hbuf, hop_wq, qwbuf);
            attn_partial_k<true><<<ABLOCKS, 256, 0, stream>>>(hfeat, nullptr, qwbuf, hop_v, mask, pl, pacc);
            attn_combine_k<<<64, 256, 0, stream>>>(pl, pacc, qbuf);
            vecmat512<<<8, 512, 0, stream>>>(qbuf, attn_wq, qwbuf);
            attn_partial_k<false><<<ABLOCKS, 256, 0, stream>>>(afeat, Abf, qwbuf, attn_v, mask, pl, pacc);
            attn_combine_k<<<64, 256, 0, stream>>>(pl, pacc, xbuf);
            score_k<<<1, 64, 0, stream>>>(xbuf, score_w, score_b, dout + s);
        }
    }
}